// Round 4
// baseline (246.204 us; speedup 1.0000x reference)
//
#include <hip/hip_runtime.h>
#include <math.h>

// ---------------------------------------------------------------------------
// ISTFTHead on gfx950 — fp16 MFMA path, round 4.
//
// Changes vs round 3 (which was LDS-read-throughput bound in both GEMMs):
//  * GEMM1 uses a 2-product split: h = (xh+xl)@Wh. The dropped xh@Wl term
//    contributes ~1e-5 to y (analysis in round log) — negligible vs 2e-3
//    current absmax. B LDS traffic halves, MFMA count -33%, LDS 24 KB,
//    launch_bounds(256,4) for 4 blocks/CU.
//  * GEMM2 exploits irfft mirror symmetry: frames[n] = C[n]+D[n],
//    frames[1024-n] = C[n]-D[n], where C = Sr@cos-basis, D = Si@(-sin)-basis,
//    computed only for n in [0,513) (padded 576). Halves GEMM2 flops and
//    basis size. Block 256m x 64n, wave 4m x 4n, dual accumulators.
//  * conv_w generates Wh only (B1 halves).
//
// Fragment order for mfma_f32_16x16x32_f16 (verified rounds 2-3):
//   A tile: elem(lane,j) = A[m = lane&15][k = (lane>>4)*8 + j]
//   B tile: elem(lane,j) = B[k = (lane>>4)*8 + j][n = lane&15]
//   C/D:    row = (lane>>4)*4 + r, col = lane&15
//
// Workspace map (bytes):
//   A2  [0,          35651584)   16384 x 1088 f16, [mb128][kt34][mts8][l][j]
//                                kt 0..16 = Sr rows (kk<544), 17..33 = Si rows
//   B2  [35651584,   36904960)   mirror basis, [nblk9][kt34][nt4][l][j]
//   A1  [37879808,   71434240)   [xh|xl],      [mblk128][kt32][mts8][l][j]
//   B1  [71434240,   72613888)   Wh,           [bx9][kt16][t8][l][j]
//   frames [37879808, 71434240)  16384 x 1024 f16 (aliases A1 — dead by GEMM2)
// ---------------------------------------------------------------------------

using half8 = __attribute__((ext_vector_type(8))) _Float16;
using f32x4 = __attribute__((ext_vector_type(4))) float;

#define TWO_PI_OVER_1024 0.006135923151542565f

#define OFF_A2 0
#define OFF_B2 35651584UL
#define OFF_A1 37879808UL
#define OFF_B1 71434240UL
#define OFF_FR 37879808UL

__device__ __forceinline__ float hannf(int s) {
    return 0.5f * (1.0f - cosf(TWO_PI_OVER_1024 * (float)s));
}

// async global->LDS, 16B per lane. Global addr per-lane; LDS dest wave-uniform.
__device__ __forceinline__ void stage16(const void* g, void* lds) {
    __builtin_amdgcn_global_load_lds(
        (const __attribute__((address_space(1))) void*)g,
        (__attribute__((address_space(3))) void*)lds,
        16, 0, 0);
}

// ---------------- conversion kernels ----------------

// x (16384x512 f32) -> A1 fragment-swizzled fp16 [xh (kt 0..15) | xl (kt 16..31)]
__global__ __launch_bounds__(256)
void conv_x_k(const float* __restrict__ x, _Float16* __restrict__ A1)
{
    const size_t tid = (size_t)blockIdx.x * 256 + threadIdx.x;   // 2,097,152
    const int l   = (int)(tid & 63);
    const size_t f = tid >> 6;
    const int mts = (int)(f & 7);
    const size_t g = f >> 3;
    const int kt  = (int)(g & 31);
    const int mtb = (int)(g >> 5);
    const int m   = mtb * 128 + mts * 16 + (l & 15);
    const int k0  = (kt & 15) * 32 + (l >> 4) * 8;
    const bool hi = (kt < 16);
    const float* xp = x + (size_t)m * 512 + k0;
    const float4 v0 = *(const float4*)xp;
    const float4 v1 = *(const float4*)(xp + 4);
    const float vv[8] = {v0.x, v0.y, v0.z, v0.w, v1.x, v1.y, v1.z, v1.w};
    half8 o;
#pragma unroll
    for (int j = 0; j < 8; ++j) {
        _Float16 h = (_Float16)vv[j];
        o[j] = hi ? h : (_Float16)(vv[j] - (float)h);
    }
    *(half8*)(A1 + tid * 8) = o;
}

// W (512x1026 f32) -> B1 (Wh only) fragment-swizzled fp16, per bx(0..8):
// tiles 0..3 = mag cols (bx*64..+63), tiles 4..7 = phase cols (513 + same).
__global__ __launch_bounds__(256)
void conv_w_k(const float* __restrict__ W, _Float16* __restrict__ B1)
{
    const int tid = blockIdx.x * 256 + threadIdx.x;              // 73,728
    const int l  = tid & 63;
    const int f  = tid >> 6;
    const int t8 = f & 7;
    const int g  = f >> 3;
    const int kt = g & 15;
    const int bx = g >> 4;
    const int side = t8 >> 2;
    const int nt   = t8 & 3;
    const int c    = bx * 64 + nt * 16 + (l & 15);               // [0,576)
    const int k0   = kt * 32 + (l >> 4) * 8;
    const int wcol = side ? (513 + c) : c;
    half8 o;
#pragma unroll
    for (int j = 0; j < 8; ++j) {
        float v = (c < 513) ? W[(size_t)(k0 + j) * 1026 + wcol] : 0.0f;
        o[j] = (_Float16)v;
    }
    *(half8*)(B1 + (size_t)tid * 8) = o;
}

// Mirror-symmetric windowed irfft basis, n in [0,576), fragment order
// [nblk9][kt34][nt4][l][j]. kk = kt*32 + (l>>4)*8 + j:
//   kk < 544 : cos row for bin kk   (pairs with Sr)
//   kk >= 544: -sin row for bin kk-544 (pairs with Si)
__global__ __launch_bounds__(256)
void basis_k(_Float16* __restrict__ B2)
{
    const int tid = blockIdx.x * 256 + threadIdx.x;              // 78,336
    const int l  = tid & 63;
    const int f  = tid >> 6;
    const int nt = f & 3;
    const int g  = f >> 2;
    const int kt = g % 34;
    const int nblk = g / 34;
    const int n  = nblk * 64 + nt * 16 + (l & 15);
    const int kk0 = kt * 32 + (l >> 4) * 8;
    const float win = hannf(n) * (1.0f / 1024.0f);
    half8 o;
#pragma unroll
    for (int j = 0; j < 8; ++j) {
        const int kk = kk0 + j;
        float v = 0.0f;
        if (kk < 544) {
            const int k = kk;
            if (k < 513) {
                const float coef = (k == 0 || k == 512) ? 1.0f : 2.0f;
                v = coef * cosf(TWO_PI_OVER_1024 * (float)((k * n) & 1023)) * win;
            }
        } else {
            const int k = kk - 544;
            if (k < 513) {
                const float coef = (k == 0 || k == 512) ? 1.0f : 2.0f;
                v = -coef * sinf(TWO_PI_OVER_1024 * (float)((k * n) & 1023)) * win;
            }
        }
        o[j] = (_Float16)v;
    }
    *(half8*)(B2 + (size_t)tid * 8) = o;
}

// ---------------- GEMM1: x@W + b, fused activation, swizzled A2 output ------

__device__ __forceinline__ void store_a2(_Float16* __restrict__ A2, int m, int k, float v)
{
    const int mt2 = m >> 4, mr = m & 15;
    const int kt2 = k >> 5, kc = k & 31;
    const int l2 = (kc >> 3) * 16 + mr;
    const int j2 = kc & 7;
    const int mtb = mt2 >> 3, mts = mt2 & 7;
    const size_t idx = ((((size_t)mtb * 34 + kt2) * 8 + mts) * 64 + l2) * 8 + j2;
    A2[idx] = (_Float16)v;
}

__global__ __launch_bounds__(256, 4)
void gemm1_k(const _Float16* __restrict__ A, const _Float16* __restrict__ B,
             const float* __restrict__ bias, _Float16* __restrict__ A2)
{
    __shared__ _Float16 Ash[8 * 512];
    __shared__ _Float16 Asl[8 * 512];
    __shared__ _Float16 Bsh[8 * 512];
    const int t = threadIdx.x, w = t >> 6, l = t & 63;

    // XCD-aware swizzle: 1152 blocks, 144 per XCD = 16 mblk x 9 bx.
    const int lin = blockIdx.x;
    const int xcd = lin & 7, slot = lin >> 3;
    const int mblk = xcd * 16 + slot / 9;
    const int bx   = slot % 9;

    f32x4 acc[2][8];
#pragma unroll
    for (int i = 0; i < 2; ++i)
#pragma unroll
        for (int j = 0; j < 8; ++j) acc[i][j] = (f32x4)0.0f;

    const _Float16* Ab = A + (size_t)mblk * (32 * 4096);
    const _Float16* Bb = B + (size_t)bx * (16 * 4096);
    const int lane16 = l * 8;
    const int w2 = 2 * w;

    for (int kt = 0; kt < 16; ++kt) {
        const _Float16* Agh = Ab + (size_t)kt * 4096 + w2 * 512 + lane16;
        const _Float16* Agl = Agh + 16 * 4096;
        const _Float16* Bgh = Bb + (size_t)kt * 4096 + w2 * 512 + lane16;
        __syncthreads();
        stage16(Agh,       &Ash[w2 * 512]);
        stage16(Agh + 512, &Ash[(w2 + 1) * 512]);
        stage16(Agl,       &Asl[w2 * 512]);
        stage16(Agl + 512, &Asl[(w2 + 1) * 512]);
        stage16(Bgh,       &Bsh[w2 * 512]);
        stage16(Bgh + 512, &Bsh[(w2 + 1) * 512]);
        __syncthreads();

        half8 ah[2], al[2];
#pragma unroll
        for (int i = 0; i < 2; ++i) {
            ah[i] = *(const half8*)&Ash[(w2 + i) * 512 + lane16];
            al[i] = *(const half8*)&Asl[(w2 + i) * 512 + lane16];
        }
#pragma unroll
        for (int j = 0; j < 8; ++j) {
            const half8 bh = *(const half8*)&Bsh[j * 512 + lane16];
            acc[0][j] = __builtin_amdgcn_mfma_f32_16x16x32_f16(ah[0], bh, acc[0][j], 0, 0, 0);
            acc[1][j] = __builtin_amdgcn_mfma_f32_16x16x32_f16(ah[1], bh, acc[1][j], 0, 0, 0);
            acc[0][j] = __builtin_amdgcn_mfma_f32_16x16x32_f16(al[0], bh, acc[0][j], 0, 0, 0);
            acc[1][j] = __builtin_amdgcn_mfma_f32_16x16x32_f16(al[1], bh, acc[1][j], 0, 0, 0);
        }
    }

    // epilogue: activation + swizzled fp16 stores
    const int r4 = (l >> 4) * 4, c16 = l & 15;
#pragma unroll
    for (int mt = 0; mt < 2; ++mt) {
        const int mbase = mblk * 128 + (w2 + mt) * 16 + r4;
#pragma unroll
        for (int nt = 0; nt < 4; ++nt) {
            const int c = bx * 64 + nt * 16 + c16;
            const bool valid = (c < 513);
            const float bm = valid ? bias[c] : 0.0f;
            const float bp = valid ? bias[513 + c] : 0.0f;
#pragma unroll
            for (int r = 0; r < 4; ++r) {
                float Sr = 0.0f, Si = 0.0f;
                if (valid) {
                    const float mag = fminf(expf(acc[mt][nt][r] + bm), 100.0f);
                    const float ph  = acc[mt][nt + 4][r] + bp;
                    Sr = mag * cosf(ph);
                    Si = mag * sinf(ph);
                }
                if (c < 544) {
                    store_a2(A2, mbase + r, c, Sr);
                    store_a2(A2, mbase + r, 544 + c, Si);
                }
            }
        }
    }
}

// ---------------- GEMM2: mirror-symmetric frames = A2 @ basis ---------------

__device__ __forceinline__ void mma16(const _Float16* __restrict__ As,
                                      const _Float16* __restrict__ Bs,
                                      int w, int lane16, f32x4 (&acc)[4][4])
{
    half8 a[4], b[4];
#pragma unroll
    for (int i = 0; i < 4; ++i) a[i] = *(const half8*)&As[(4 * w + i) * 512 + lane16];
#pragma unroll
    for (int j = 0; j < 4; ++j) b[j] = *(const half8*)&Bs[j * 512 + lane16];
#pragma unroll
    for (int i = 0; i < 4; ++i)
#pragma unroll
        for (int j = 0; j < 4; ++j)
            acc[i][j] = __builtin_amdgcn_mfma_f32_16x16x32_f16(a[i], b[j], acc[i][j], 0, 0, 0);
}

__global__ __launch_bounds__(256, 2)
void gemm2_k(const _Float16* __restrict__ A, const _Float16* __restrict__ B,
             _Float16* __restrict__ C)
{
    __shared__ _Float16 As[16 * 512];   // 256 m-rows x 32 k
    __shared__ _Float16 Bs[4 * 512];    // 64 n-cols x 32 k
    const int t = threadIdx.x, w = t >> 6, l = t & 63;

    // XCD-aware swizzle: 576 blocks, 72 per XCD = 8 mblk x 9 nblk.
    const int lin = blockIdx.x;
    const int xcd = lin & 7, slot = lin >> 3;
    const int mblk = xcd * 8 + slot / 9;   // 256-row chunk, [0,64)
    const int nblk = slot % 9;             // 64-col chunk,  [0,9)

    f32x4 accC[4][4], accD[4][4];
#pragma unroll
    for (int i = 0; i < 4; ++i)
#pragma unroll
        for (int j = 0; j < 4; ++j) { accC[i][j] = (f32x4)0.0f; accD[i][j] = (f32x4)0.0f; }

    const int lane16 = l * 8;

    for (int kt = 0; kt < 34; ++kt) {
        __syncthreads();
        // stage A: 16 m-tiles (256 rows), wave w does tiles 4w..4w+3
#pragma unroll
        for (int i = 0; i < 4; ++i) {
            const int tt = 4 * w + i;
            const int mb128 = mblk * 2 + (tt >> 3);
            const int mts = tt & 7;
            const _Float16* Ag = A + ((((size_t)mb128 * 34 + kt) * 8 + mts) * 512) + lane16;
            stage16(Ag, &As[tt * 512]);
        }
        // stage B: 4 n-tiles, wave w does tile w
        {
            const _Float16* Bg = B + ((((size_t)nblk * 34 + kt) * 4 + w) * 512) + lane16;
            stage16(Bg, &Bs[w * 512]);
        }
        __syncthreads();

        if (kt < 17) mma16(As, Bs, w, lane16, accC);
        else         mma16(As, Bs, w, lane16, accD);
    }

    // epilogue: frames[n] = C+D, frames[1024-n] = C-D
    const int r4 = (l >> 4) * 4, c0 = l & 15;
#pragma unroll
    for (int i = 0; i < 4; ++i) {
        const int m = mblk * 256 + (4 * w + i) * 16 + r4;
#pragma unroll
        for (int j = 0; j < 4; ++j) {
            const int n = nblk * 64 + j * 16 + c0;
#pragma unroll
            for (int r = 0; r < 4; ++r) {
                const float cv = accC[i][j][r];
                const float dv = accD[i][j][r];
                _Float16* row = C + (size_t)(m + r) * 1024;
                if (n < 513)          row[n]        = (_Float16)(cv + dv);
                if (n >= 1 && n < 512) row[1024 - n] = (_Float16)(cv - dv);
            }
        }
    }
}

// ---------------- overlap-add + envelope ------------------------------------

__global__ __launch_bounds__(256)
void ola_kernel(const _Float16* __restrict__ frames, float* __restrict__ out)
{
    const int idx = blockIdx.x * 256 + threadIdx.x;   // over 8 * 524288
    const int b = idx >> 19;
    const int j = idx & 524287;
    const int n = j + 384;

    int t_hi = n >> 8;
    if (t_hi > 2047) t_hi = 2047;
    const int t_lo = (n >= 1023) ? ((n - 1023 + 255) >> 8) : 0;

    float acc = 0.0f, env = 0.0f;
    for (int tt = t_lo; tt <= t_hi; ++tt) {
        const int s = n - (tt << 8);
        const float wv = hannf(s);
        acc += (float)frames[(((size_t)(b * 2048 + tt)) << 10) + s];
        env += wv * wv;
    }
    out[idx] = acc / env;
}

// ---------------- launch ----------------------------------------------------

extern "C" void kernel_launch(void* const* d_in, const int* in_sizes, int n_in,
                              void* d_out, int out_size, void* d_ws, size_t ws_size,
                              hipStream_t stream)
{
    const float* x = (const float*)d_in[0];   // 16384 x 512
    const float* W = (const float*)d_in[1];   // 512 x 1026
    const float* b = (const float*)d_in[2];   // 1026
    float* out = (float*)d_out;               // 8 x 524288
    char* ws = (char*)d_ws;

    _Float16* A2 = (_Float16*)(ws + OFF_A2);
    _Float16* B2 = (_Float16*)(ws + OFF_B2);
    _Float16* A1 = (_Float16*)(ws + OFF_A1);
    _Float16* B1 = (_Float16*)(ws + OFF_B1);
    _Float16* frames = (_Float16*)(ws + OFF_FR);

    conv_x_k<<<8192, 256, 0, stream>>>(x, A1);
    conv_w_k<<<288, 256, 0, stream>>>(W, B1);
    basis_k<<<306, 256, 0, stream>>>(B2);

    gemm1_k<<<1152, 256, 0, stream>>>(A1, B1, b, A2);
    gemm2_k<<<576, 256, 0, stream>>>(A2, B2, frames);

    ola_kernel<<<out_size / 256, 256, 0, stream>>>(frames, out);
}

// Round 6
// 212.234 us; speedup vs baseline: 1.1601x; 1.1601x over previous
//
#include <hip/hip_runtime.h>
#include <math.h>

// ---------------------------------------------------------------------------
// ISTFTHead on gfx950 — fp16 MFMA path, round 6.
//
// Round-5 post-mortem: basis_k was launched with 2448 blocks (thread count
// computed from half-count, not half8-count) — 8x too many threads, writing
// 10 MB past B2 and clobbering the first ~7.8 MB of A1 -> absmax 0.379.
// Round 6 = round 5 with the ONE-LINE fix: basis_k grid 2448 -> 306.
//
// Structure (unchanged from round 5):
//  * GEMM1: 2 k-tiles per barrier -> 8 barrier-steps, 256 MFMA/step/block,
//    48 KB LDS, launch_bounds(256,3).
//  * GEMM2: mirror-symmetric, 128m x 96n tiles, 2 k-tiles per barrier ->
//    17 steps, dual accC/accD, grid = 768 blocks = 3/CU residency.
//
// Fragment order for mfma_f32_16x16x32_f16 (verified rounds 2-4):
//   A tile: elem(lane,j) = A[m = lane&15][k = (lane>>4)*8 + j]
//   B tile: elem(lane,j) = B[k = (lane>>4)*8 + j][n = lane&15]
//   C/D:    row = (lane>>4)*4 + r, col = lane&15
//
// Workspace map (bytes):
//   A2  [0,          35651584)   16384 x 1088 f16, [mb128][kt34][mts8][l][j]
//                                kt 0..16 = Sr rows, 17..33 = Si rows
//   B2  [35651584,   36904960)   mirror basis, [nblk6][kt34][nt6][l][j]
//   A1  [37879808,   71434240)   [xh|xl],      [mblk128][kt32][mts8][l][j]
//   B1  [71434240,   72613888)   Wh,           [bx9][kt16][t8][l][j]
//   frames [37879808, 71434240)  16384 x 1024 f16 (aliases A1 — dead by GEMM2)
// ---------------------------------------------------------------------------

using half8 = __attribute__((ext_vector_type(8))) _Float16;
using f32x4 = __attribute__((ext_vector_type(4))) float;

#define TWO_PI_OVER_1024 0.006135923151542565f

#define OFF_A2 0
#define OFF_B2 35651584UL
#define OFF_A1 37879808UL
#define OFF_B1 71434240UL
#define OFF_FR 37879808UL

__device__ __forceinline__ float hannf(int s) {
    return 0.5f * (1.0f - cosf(TWO_PI_OVER_1024 * (float)s));
}

// async global->LDS, 16B per lane. Global addr per-lane; LDS dest wave-uniform.
__device__ __forceinline__ void stage16(const void* g, void* lds) {
    __builtin_amdgcn_global_load_lds(
        (const __attribute__((address_space(1))) void*)g,
        (__attribute__((address_space(3))) void*)lds,
        16, 0, 0);
}

// ---------------- conversion kernels ----------------

// x (16384x512 f32) -> A1 fragment-swizzled fp16 [xh (kt 0..15) | xl (kt 16..31)]
__global__ __launch_bounds__(256)
void conv_x_k(const float* __restrict__ x, _Float16* __restrict__ A1)
{
    const size_t tid = (size_t)blockIdx.x * 256 + threadIdx.x;   // 2,097,152
    const int l   = (int)(tid & 63);
    const size_t f = tid >> 6;
    const int mts = (int)(f & 7);
    const size_t g = f >> 3;
    const int kt  = (int)(g & 31);
    const int mtb = (int)(g >> 5);
    const int m   = mtb * 128 + mts * 16 + (l & 15);
    const int k0  = (kt & 15) * 32 + (l >> 4) * 8;
    const bool hi = (kt < 16);
    const float* xp = x + (size_t)m * 512 + k0;
    const float4 v0 = *(const float4*)xp;
    const float4 v1 = *(const float4*)(xp + 4);
    const float vv[8] = {v0.x, v0.y, v0.z, v0.w, v1.x, v1.y, v1.z, v1.w};
    half8 o;
#pragma unroll
    for (int j = 0; j < 8; ++j) {
        _Float16 h = (_Float16)vv[j];
        o[j] = hi ? h : (_Float16)(vv[j] - (float)h);
    }
    *(half8*)(A1 + tid * 8) = o;
}

// W (512x1026 f32) -> B1 (Wh only) fragment-swizzled fp16, per bx(0..8):
// tiles 0..3 = mag cols (bx*64..+63), tiles 4..7 = phase cols (513 + same).
__global__ __launch_bounds__(256)
void conv_w_k(const float* __restrict__ W, _Float16* __restrict__ B1)
{
    const int tid = blockIdx.x * 256 + threadIdx.x;              // 73,728
    const int l  = tid & 63;
    const int f  = tid >> 6;
    const int t8 = f & 7;
    const int g  = f >> 3;
    const int kt = g & 15;
    const int bx = g >> 4;
    const int side = t8 >> 2;
    const int nt   = t8 & 3;
    const int c    = bx * 64 + nt * 16 + (l & 15);               // [0,576)
    const int k0   = kt * 32 + (l >> 4) * 8;
    const int wcol = side ? (513 + c) : c;
    half8 o;
#pragma unroll
    for (int j = 0; j < 8; ++j) {
        float v = (c < 513) ? W[(size_t)(k0 + j) * 1026 + wcol] : 0.0f;
        o[j] = (_Float16)v;
    }
    *(half8*)(B1 + (size_t)tid * 8) = o;
}

// Mirror-symmetric windowed irfft basis, n in [0,576), fragment order
// [nblk6][kt34][nt6][l][j]. kk = kt*32 + (l>>4)*8 + j:
//   kk < 544 : cos row for bin kk   (pairs with Sr)
//   kk >= 544: -sin row for bin kk-544 (pairs with Si)
// 78,336 threads (= 626,688 halfs / 8 per thread) -> 306 blocks.
__global__ __launch_bounds__(256)
void basis_k(_Float16* __restrict__ B2)
{
    const int tid = blockIdx.x * 256 + threadIdx.x;              // 78,336
    const int l  = tid & 63;
    const int f  = tid >> 6;
    const int nt = f % 6;
    const int g  = f / 6;
    const int kt = g % 34;
    const int nblk = g / 34;
    const int n  = nblk * 96 + nt * 16 + (l & 15);
    const int kk0 = kt * 32 + (l >> 4) * 8;
    const float win = hannf(n) * (1.0f / 1024.0f);
    half8 o;
#pragma unroll
    for (int j = 0; j < 8; ++j) {
        const int kk = kk0 + j;
        float v = 0.0f;
        if (kk < 544) {
            const int k = kk;
            if (k < 513) {
                const float coef = (k == 0 || k == 512) ? 1.0f : 2.0f;
                v = coef * cosf(TWO_PI_OVER_1024 * (float)((k * n) & 1023)) * win;
            }
        } else {
            const int k = kk - 544;
            if (k < 513) {
                const float coef = (k == 0 || k == 512) ? 1.0f : 2.0f;
                v = -coef * sinf(TWO_PI_OVER_1024 * (float)((k * n) & 1023)) * win;
            }
        }
        o[j] = (_Float16)v;
    }
    *(half8*)(B2 + (size_t)tid * 8) = o;
}

// ---------------- GEMM1: x@W + b, fused activation, swizzled A2 output ------

__device__ __forceinline__ void store_a2(_Float16* __restrict__ A2, int m, int k, float v)
{
    const int mt2 = m >> 4, mr = m & 15;
    const int kt2 = k >> 5, kc = k & 31;
    const int l2 = (kc >> 3) * 16 + mr;
    const int j2 = kc & 7;
    const int mtb = mt2 >> 3, mts = mt2 & 7;
    const size_t idx = ((((size_t)mtb * 34 + kt2) * 8 + mts) * 64 + l2) * 8 + j2;
    A2[idx] = (_Float16)v;
}

__global__ __launch_bounds__(256, 3)
void gemm1_k(const _Float16* __restrict__ A, const _Float16* __restrict__ B,
             const float* __restrict__ bias, _Float16* __restrict__ A2)
{
    __shared__ _Float16 Ash[2][8 * 512];
    __shared__ _Float16 Asl[2][8 * 512];
    __shared__ _Float16 Bsh[2][8 * 512];
    const int t = threadIdx.x, w = t >> 6, l = t & 63;

    // XCD-aware swizzle: 1152 blocks, 144 per XCD = 16 mblk x 9 bx.
    const int lin = blockIdx.x;
    const int xcd = lin & 7, slot = lin >> 3;
    const int mblk = xcd * 16 + slot / 9;
    const int bx   = slot % 9;

    f32x4 acc[2][8];
#pragma unroll
    for (int i = 0; i < 2; ++i)
#pragma unroll
        for (int j = 0; j < 8; ++j) acc[i][j] = (f32x4)0.0f;

    const _Float16* Ab = A + (size_t)mblk * (32 * 4096);
    const _Float16* Bb = B + (size_t)bx * (16 * 4096);
    const int lane16 = l * 8;
    const int w2 = 2 * w;

    for (int step = 0; step < 8; ++step) {
        const int kt = 2 * step;
        __syncthreads();
#pragma unroll
        for (int u = 0; u < 2; ++u) {
            const _Float16* Agh = Ab + (size_t)(kt + u) * 4096 + w2 * 512 + lane16;
            const _Float16* Agl = Agh + 16 * 4096;
            const _Float16* Bgh = Bb + (size_t)(kt + u) * 4096 + w2 * 512 + lane16;
            stage16(Agh,       &Ash[u][w2 * 512]);
            stage16(Agh + 512, &Ash[u][(w2 + 1) * 512]);
            stage16(Agl,       &Asl[u][w2 * 512]);
            stage16(Agl + 512, &Asl[u][(w2 + 1) * 512]);
            stage16(Bgh,       &Bsh[u][w2 * 512]);
            stage16(Bgh + 512, &Bsh[u][(w2 + 1) * 512]);
        }
        __syncthreads();

#pragma unroll
        for (int u = 0; u < 2; ++u) {
            half8 ah[2], al[2];
#pragma unroll
            for (int i = 0; i < 2; ++i) {
                ah[i] = *(const half8*)&Ash[u][(w2 + i) * 512 + lane16];
                al[i] = *(const half8*)&Asl[u][(w2 + i) * 512 + lane16];
            }
#pragma unroll
            for (int j = 0; j < 8; ++j) {
                const half8 bh = *(const half8*)&Bsh[u][j * 512 + lane16];
                acc[0][j] = __builtin_amdgcn_mfma_f32_16x16x32_f16(ah[0], bh, acc[0][j], 0, 0, 0);
                acc[1][j] = __builtin_amdgcn_mfma_f32_16x16x32_f16(ah[1], bh, acc[1][j], 0, 0, 0);
                acc[0][j] = __builtin_amdgcn_mfma_f32_16x16x32_f16(al[0], bh, acc[0][j], 0, 0, 0);
                acc[1][j] = __builtin_amdgcn_mfma_f32_16x16x32_f16(al[1], bh, acc[1][j], 0, 0, 0);
            }
        }
    }

    // epilogue: activation + swizzled fp16 stores
    const int r4 = (l >> 4) * 4, c16 = l & 15;
#pragma unroll
    for (int mt = 0; mt < 2; ++mt) {
        const int mbase = mblk * 128 + (w2 + mt) * 16 + r4;
#pragma unroll
        for (int nt = 0; nt < 4; ++nt) {
            const int c = bx * 64 + nt * 16 + c16;
            const bool valid = (c < 513);
            const float bm = valid ? bias[c] : 0.0f;
            const float bp = valid ? bias[513 + c] : 0.0f;
#pragma unroll
            for (int r = 0; r < 4; ++r) {
                float Sr = 0.0f, Si = 0.0f;
                if (valid) {
                    const float mag = fminf(expf(acc[mt][nt][r] + bm), 100.0f);
                    const float ph  = acc[mt][nt + 4][r] + bp;
                    Sr = mag * cosf(ph);
                    Si = mag * sinf(ph);
                }
                if (c < 544) {
                    store_a2(A2, mbase + r, c, Sr);
                    store_a2(A2, mbase + r, 544 + c, Si);
                }
            }
        }
    }
}

// ---------------- GEMM2: mirror-symmetric frames = A2 @ basis ---------------
// Block: 128 m-rows x 96 n-cols. 2 k-tiles per barrier, 17 steps over K=1088.
// kt < 17 accumulates into accC (cos/Sr), kt >= 17 into accD (sin/Si).

__device__ __forceinline__ void mma43(const _Float16* __restrict__ As,
                                      const _Float16* __restrict__ Bs,
                                      int wm, int wn, int lane16, f32x4 (&acc)[4][3])
{
    half8 a[4], b[3];
#pragma unroll
    for (int i = 0; i < 4; ++i) a[i] = *(const half8*)&As[(wm + i) * 512 + lane16];
#pragma unroll
    for (int j = 0; j < 3; ++j) b[j] = *(const half8*)&Bs[(wn + j) * 512 + lane16];
#pragma unroll
    for (int i = 0; i < 4; ++i)
#pragma unroll
        for (int j = 0; j < 3; ++j)
            acc[i][j] = __builtin_amdgcn_mfma_f32_16x16x32_f16(a[i], b[j], acc[i][j], 0, 0, 0);
}

__global__ __launch_bounds__(256, 3)
void gemm2_k(const _Float16* __restrict__ A, const _Float16* __restrict__ Bas,
             _Float16* __restrict__ C)
{
    __shared__ _Float16 As[2][8 * 512];   // 2 k-tiles x 128 m-rows
    __shared__ _Float16 Bs[2][6 * 512];   // 2 k-tiles x 96 n-cols
    const int t = threadIdx.x, w = t >> 6, l = t & 63;

    // XCD-aware swizzle: 768 blocks, 96 per XCD = 16 mblk x 6 nblk.
    const int lin = blockIdx.x;
    const int xcd = lin & 7, slot = lin >> 3;
    const int mblk = xcd * 16 + slot / 6;   // [0,128) — 128-row chunk
    const int nblk = slot % 6;              // [0,6)   — 96-col chunk

    // wave grid 2x2: wave covers 4 m-tiles x 3 n-tiles
    const int wm = (w & 1) * 4, wn = (w >> 1) * 3;

    f32x4 accC[4][3], accD[4][3];
#pragma unroll
    for (int i = 0; i < 4; ++i)
#pragma unroll
        for (int j = 0; j < 3; ++j) { accC[i][j] = (f32x4)0.0f; accD[i][j] = (f32x4)0.0f; }

    const int lane16 = l * 8;

    for (int step = 0; step < 17; ++step) {
        const int kt0 = 2 * step;
        __syncthreads();
        // stage A: 16 tiles (2 kt x 8 mts); wave w does ta = 4w..4w+3
#pragma unroll
        for (int i = 0; i < 4; ++i) {
            const int ta = 4 * w + i;
            const int u = ta >> 3, mts = ta & 7;
            const _Float16* Ag = A + ((((size_t)mblk * 34 + (kt0 + u)) * 8 + mts) * 512) + lane16;
            stage16(Ag, &As[u][mts * 512]);
        }
        // stage B: 12 tiles (2 kt x 6 nt); wave w does tb = 3w..3w+2
#pragma unroll
        for (int i = 0; i < 3; ++i) {
            const int tb = 3 * w + i;
            const int u = tb / 6, nt = tb % 6;
            const _Float16* Bg = Bas + ((((size_t)nblk * 34 + (kt0 + u)) * 6 + nt) * 512) + lane16;
            stage16(Bg, &Bs[u][nt * 512]);
        }
        __syncthreads();

#pragma unroll
        for (int u = 0; u < 2; ++u) {
            const int kt = kt0 + u;
            if (kt < 17) mma43(As[u], Bs[u], wm, wn, lane16, accC);
            else         mma43(As[u], Bs[u], wm, wn, lane16, accD);
        }
    }

    // epilogue: frames[n] = C+D, frames[1024-n] = C-D  (hann(1024-n)=hann(n))
    const int r4 = (l >> 4) * 4, c0 = l & 15;
#pragma unroll
    for (int i = 0; i < 4; ++i) {
        const int m = mblk * 128 + (wm + i) * 16 + r4;
#pragma unroll
        for (int j = 0; j < 3; ++j) {
            const int n = nblk * 96 + (wn + j) * 16 + c0;
#pragma unroll
            for (int r = 0; r < 4; ++r) {
                const float cv = accC[i][j][r];
                const float dv = accD[i][j][r];
                _Float16* row = C + (size_t)(m + r) * 1024;
                if (n < 513)           row[n]        = (_Float16)(cv + dv);
                if (n >= 1 && n < 512) row[1024 - n] = (_Float16)(cv - dv);
            }
        }
    }
}

// ---------------- overlap-add + envelope ------------------------------------

__global__ __launch_bounds__(256)
void ola_kernel(const _Float16* __restrict__ frames, float* __restrict__ out)
{
    const int idx = blockIdx.x * 256 + threadIdx.x;   // over 8 * 524288
    const int b = idx >> 19;
    const int j = idx & 524287;
    const int n = j + 384;

    int t_hi = n >> 8;
    if (t_hi > 2047) t_hi = 2047;
    const int t_lo = (n >= 1023) ? ((n - 1023 + 255) >> 8) : 0;

    float acc = 0.0f, env = 0.0f;
    for (int tt = t_lo; tt <= t_hi; ++tt) {
        const int s = n - (tt << 8);
        const float wv = hannf(s);
        acc += (float)frames[(((size_t)(b * 2048 + tt)) << 10) + s];
        env += wv * wv;
    }
    out[idx] = acc / env;
}

// ---------------- launch ----------------------------------------------------

extern "C" void kernel_launch(void* const* d_in, const int* in_sizes, int n_in,
                              void* d_out, int out_size, void* d_ws, size_t ws_size,
                              hipStream_t stream)
{
    const float* x = (const float*)d_in[0];   // 16384 x 512
    const float* W = (const float*)d_in[1];   // 512 x 1026
    const float* b = (const float*)d_in[2];   // 1026
    float* out = (float*)d_out;               // 8 x 524288
    char* ws = (char*)d_ws;

    _Float16* A2 = (_Float16*)(ws + OFF_A2);
    _Float16* B2 = (_Float16*)(ws + OFF_B2);
    _Float16* A1 = (_Float16*)(ws + OFF_A1);
    _Float16* B1 = (_Float16*)(ws + OFF_B1);
    _Float16* frames = (_Float16*)(ws + OFF_FR);

    conv_x_k<<<8192, 256, 0, stream>>>(x, A1);
    conv_w_k<<<288, 256, 0, stream>>>(W, B1);
    basis_k<<<306, 256, 0, stream>>>(B2);   // 78,336 threads — NOT 2448 blocks

    gemm1_k<<<1152, 256, 0, stream>>>(A1, B1, b, A2);
    gemm2_k<<<768, 256, 0, stream>>>(A2, B2, frames);

    ola_kernel<<<out_size / 256, 256, 0, stream>>>(frames, out);
}